// Round 6
// baseline (782.641 us; speedup 1.0000x reference)
//
#include <hip/hip_runtime.h>
#include <math.h>

#define NTN 32768
#define BB 16
#define NN 2048
#define IN_CH 128
#define HC 256
#define EREAL 524288
#define ETOT (EREAL + NTN)
#define FC0 1024
#define FC1 512
#define OMIC 128
#define OUTD 2
#define CAP 96

#define PREP_BLKS (NTN / 4)
#define DEG_BLKS (EREAL / 256)
#define CASTW_BLKS ((HC * IN_CH + HC * HC) / 256)
#define GEMM_YB (NTN / 128)
#define FILL_YB 512   // 512*4 blocks * 256 threads = 524288 edges

typedef __attribute__((ext_vector_type(8))) short bf16x8;
typedef __attribute__((ext_vector_type(4))) float f32x4;
typedef __attribute__((ext_vector_type(2))) float f32x2;

static __device__ __forceinline__ float wave_sum(float v) {
    for (int o = 32; o; o >>= 1) v += __shfl_xor(v, o);
    return v;
}
static __device__ __forceinline__ unsigned short f2bf(float f) {
    unsigned u = __float_as_uint(f);
    unsigned r = (u + 0x7fff + ((u >> 16) & 1)) >> 16;
    return (unsigned short)r;
}
// R16: wave-local LDS producer->consumer fence
static __device__ __forceinline__ void wave_sync() {
    asm volatile("s_waitcnt lgkmcnt(0)" ::: "memory");
    __builtin_amdgcn_sched_barrier(0);
}
static __device__ __forceinline__ void pkfma(f32x2& acc, f32x2 ab, f32x2 e2) {
    asm("v_pk_fma_f32 %0, %1, %2, %0" : "+v"(acc) : "v"(ab), "v"(e2));
}
static __device__ __forceinline__ void fma8pk(uint4 v, f32x2 e2, f32x2* acc) {
    f32x2 p;
    p.x = __uint_as_float(v.x << 16); p.y = __uint_as_float(v.x & 0xffff0000u);
    pkfma(acc[0], p, e2);
    p.x = __uint_as_float(v.y << 16); p.y = __uint_as_float(v.y & 0xffff0000u);
    pkfma(acc[1], p, e2);
    p.x = __uint_as_float(v.z << 16); p.y = __uint_as_float(v.z & 0xffff0000u);
    pkfma(acc[2], p, e2);
    p.x = __uint_as_float(v.w << 16); p.y = __uint_as_float(v.w & 0xffff0000u);
    pkfma(acc[3], p, e2);
}
// R14: bf16 dot2 hot loop (v_perm pair-build + v_dot2_f32_bf16)
static __device__ __forceinline__ void dot2bf(float& acc, unsigned px, unsigned pe) {
    asm("v_dot2_f32_bf16 %0, %1, %2, %0" : "+v"(acc) : "v"(px), "v"(pe));
}
static __device__ __forceinline__ void dot8x2(uint4 a, uint4 b, unsigned pe, float* acc) {
    unsigned p;
    p = __builtin_amdgcn_perm(a.x, b.x, 0x01000504u); dot2bf(acc[0], p, pe);
    p = __builtin_amdgcn_perm(a.x, b.x, 0x03020706u); dot2bf(acc[1], p, pe);
    p = __builtin_amdgcn_perm(a.y, b.y, 0x01000504u); dot2bf(acc[2], p, pe);
    p = __builtin_amdgcn_perm(a.y, b.y, 0x03020706u); dot2bf(acc[3], p, pe);
    p = __builtin_amdgcn_perm(a.z, b.z, 0x01000504u); dot2bf(acc[4], p, pe);
    p = __builtin_amdgcn_perm(a.z, b.z, 0x03020706u); dot2bf(acc[5], p, pe);
    p = __builtin_amdgcn_perm(a.w, b.w, 0x01000504u); dot2bf(acc[6], p, pe);
    p = __builtin_amdgcn_perm(a.w, b.w, 0x03020706u); dot2bf(acc[7], p, pe);
}

// ---- fused: x->bf16 + mean (+R18 LN stats0 atomics) | deg count | weight casts ----
__global__ __launch_bounds__(256) void k_pre(
    const float* __restrict__ x, unsigned short* __restrict__ xb, float* __restrict__ xmean,
    const int* __restrict__ ei, int* __restrict__ deg, int* __restrict__ epos,
    const float* __restrict__ w1, const float* __restrict__ w2,
    unsigned short* __restrict__ w1t, unsigned short* __restrict__ w2t,
    float* __restrict__ stats0) {
    int b = blockIdx.x, t = threadIdx.x;
    if (b < PREP_BLKS) {
        __shared__ float sb[4];
        int wave = t >> 6, lane = t & 63;
        int n = b * 4 + wave;
        float2 v = *(const float2*)(x + (size_t)n * IN_CH + lane * 2);
        ushort2 o;
        o.x = f2bf(v.x); o.y = f2bf(v.y);
        *(ushort2*)(xb + (size_t)n * IN_CH + lane * 2) = o;
        float s = wave_sum(v.x + v.y);
        if (lane == 0) { float m = s * (1.0f / 128.0f); xmean[n] = m; sb[wave] = m; }
        __syncthreads();
        if (t == 0) {
            float su = 0.f, sq = 0.f;
#pragma unroll
            for (int j = 0; j < 4; j++) { float m = sb[j]; su += m; sq += m * m; }
            int row = b >> 9;
            atomicAdd(&stats0[row * 2], su);
            atomicAdd(&stats0[row * 2 + 1], sq);
        }
    } else if (b < PREP_BLKS + DEG_BLKS) {
        int e = (b - PREP_BLKS) * 256 + t;
        int d = ei[EREAL + e];
        epos[e] = atomicAdd(&deg[d], 1);
    } else {
        int idx = (b - PREP_BLKS - DEG_BLKS) * 256 + t;
        if (idx < HC * IN_CH) {
            int n = idx / IN_CH, k = idx % IN_CH;
            w1t[idx] = f2bf(w1[(size_t)k * HC + n]);
        } else {
            int j = idx - HC * IN_CH;
            int n = j / HC, k = j % HC;
            w2t[j] = f2bf(w2[(size_t)k * HC + n]);
        }
    }
}

// ---- scan degrees -> rowptr; write self-loop at slot 0 of each segment ----
__global__ __launch_bounds__(1024) void k_scan(const int* __restrict__ deg, int* __restrict__ rowptr,
                                               int* __restrict__ csr) {
    __shared__ int sd[1024];
    int t = threadIdx.x;
    int base = t * 32;
    int loc[32];
    int s = 0;
#pragma unroll
    for (int j = 0; j < 32; j++) { int d = deg[base + j] + 1; loc[j] = d; s += d; }
    sd[t] = s; __syncthreads();
    for (int o = 1; o < 1024; o <<= 1) {
        int v = (t >= o) ? sd[t - o] : 0;
        __syncthreads();
        sd[t] += v;
        __syncthreads();
    }
    int run = sd[t] - s;  // exclusive prefix
#pragma unroll
    for (int j = 0; j < 32; j++) {
        rowptr[base + j] = run;
        csr[run] = base + j;   // self-loop at slot 0
        run += loc[j];
    }
    if (t == 1023) rowptr[NTN] = run;
}

// ---- bf16 MFMA GEMM (+ optional fused CSR-fill blocks at by >= GEMM_YB) ----
__global__ __launch_bounds__(256) void k_gemm_mfma(
    const unsigned short* __restrict__ A, const unsigned short* __restrict__ Bt, int K,
    const float* __restrict__ attS, const float* __restrict__ attD,
    unsigned short* __restrict__ Cout, float* __restrict__ aS, float* __restrict__ aD,
    const int* __restrict__ ei, const int* __restrict__ epos,
    const int* __restrict__ rowptr, int* __restrict__ csr) {
    __shared__ unsigned short As[128][72];
    __shared__ unsigned short Bs[64][72];
    const int t = threadIdx.x;
    const int bx = blockIdx.x, by = blockIdx.y;
    if (by >= GEMM_YB) {
        int e = (((by - GEMM_YB) * 4 + bx)) * 256 + t;
        int s = ei[e], d = ei[EREAL + e];
        csr[rowptr[d] + 1 + epos[e]] = s;
        return;
    }
    const int lane = t & 63, wave = t >> 6;
    const int quad = lane >> 4, l16 = lane & 15;
    const int arow = t >> 1, acol = (t & 1) * 32;
    const int brow = t >> 2, bcol = (t & 3) * 16;
    const unsigned short* Ag = A + (size_t)(by * 128 + arow) * K + acol;
    const unsigned short* Bg = Bt + (size_t)(bx * 64 + brow) * K + bcol;
    f32x4 acc[2][4] = {};
    for (int k0 = 0; k0 < K; k0 += 64) {
        uint4 a0 = *(const uint4*)(Ag + k0);
        uint4 a1 = *(const uint4*)(Ag + k0 + 8);
        uint4 a2 = *(const uint4*)(Ag + k0 + 16);
        uint4 a3 = *(const uint4*)(Ag + k0 + 24);
        uint4 b0 = *(const uint4*)(Bg + k0);
        uint4 b1 = *(const uint4*)(Bg + k0 + 8);
        __syncthreads();
        *(uint4*)&As[arow][acol +  0] = a0;
        *(uint4*)&As[arow][acol +  8] = a1;
        *(uint4*)&As[arow][acol + 16] = a2;
        *(uint4*)&As[arow][acol + 24] = a3;
        *(uint4*)&Bs[brow][bcol +  0] = b0;
        *(uint4*)&Bs[brow][bcol +  8] = b1;
        __syncthreads();
#pragma unroll
        for (int kc = 0; kc < 64; kc += 32) {
            bf16x8 af[2], bfr[4];
#pragma unroll
            for (int mt = 0; mt < 2; mt++)
                af[mt] = *(const bf16x8*)&As[wave * 32 + mt * 16 + l16][kc + quad * 8];
#pragma unroll
            for (int nt = 0; nt < 4; nt++)
                bfr[nt] = *(const bf16x8*)&Bs[nt * 16 + l16][kc + quad * 8];
#pragma unroll
            for (int mt = 0; mt < 2; mt++)
#pragma unroll
                for (int nt = 0; nt < 4; nt++)
                    acc[mt][nt] = __builtin_amdgcn_mfma_f32_16x16x32_bf16(af[mt], bfr[nt], acc[mt][nt], 0, 0, 0);
        }
    }
    float as_l[4], ad_l[4];
#pragma unroll
    for (int nt = 0; nt < 4; nt++) {
        int gcol = bx * 64 + nt * 16 + l16;
        as_l[nt] = attS[gcol];
        ad_l[nt] = attD[gcol];
    }
#pragma unroll
    for (int mt = 0; mt < 2; mt++) {
#pragma unroll
        for (int reg = 0; reg < 4; reg++) {
            int grow = by * 128 + wave * 32 + mt * 16 + quad * 4 + reg;
            float ps = 0.f, pd = 0.f;
#pragma unroll
            for (int nt = 0; nt < 4; nt++) {
                float v = acc[mt][nt][reg];
                Cout[(size_t)grow * HC + bx * 64 + nt * 16 + l16] = f2bf(v);
                ps += v * as_l[nt];
                pd += v * ad_l[nt];
            }
            for (int o = 8; o; o >>= 1) { ps += __shfl_xor(ps, o); pd += __shfl_xor(pd, o); }
            if (l16 == 0) { aS[grow * 4 + bx] = ps; aD[grow * 4 + bx] = pd; }
        }
    }
}

// ---- attention aggregate (R16: 1 wave = 1 node; R18: + LN stats atomics) ----
__global__ __launch_bounds__(256) void k_agg(
    const unsigned short* __restrict__ xw, const float* __restrict__ aS, const float* __restrict__ aD,
    const int* __restrict__ rowptr, const int* __restrict__ csr,
    const float* __restrict__ bias, const float* __restrict__ poolw, const float* __restrict__ poolb,
    unsigned short* __restrict__ hout, float* __restrict__ xpre, float* __restrict__ stats) {
    __shared__ float ea_s[4][CAP][4];
    __shared__ int   ss[4][CAP];
    __shared__ float pshare[4];
    int t = threadIdx.x;
    int w = t >> 6, lane = t & 63;
    int n = blockIdx.x * 4 + w;
    int beg = rowptr[n], end = rowptr[n + 1];
    int deg = end - beg;
    float4 ad4 = *(const float4*)(aD + n * 4);
    float l0 = 0.f, l1 = 0.f, l2 = 0.f, l3 = 0.f;
    if (deg <= CAP) {
        for (int i = lane; i < deg; i += 64) {
            int s = csr[beg + i];
            ss[w][i] = s << 9;
            float4 as4 = *(const float4*)(aS + s * 4);
            float a0 = as4.x + ad4.x; a0 = a0 > 0.f ? a0 : 0.2f * a0;
            float a1 = as4.y + ad4.y; a1 = a1 > 0.f ? a1 : 0.2f * a1;
            float a2 = as4.z + ad4.z; a2 = a2 > 0.f ? a2 : 0.2f * a2;
            float a3 = as4.w + ad4.w; a3 = a3 > 0.f ? a3 : 0.2f * a3;
            float4 e4;
            e4.x = __expf(a0); e4.y = __expf(a1); e4.z = __expf(a2); e4.w = __expf(a3);
            *(float4*)&ea_s[w][i][0] = e4;
        }
        wave_sync();
    } else {
        for (int i = lane; i < deg; i += 64) {
            int s = csr[beg + i];
            float4 as4 = *(const float4*)(aS + s * 4);
            float a0 = as4.x + ad4.x; a0 = a0 > 0.f ? a0 : 0.2f * a0; l0 += __expf(a0);
            float a1 = as4.y + ad4.y; a1 = a1 > 0.f ? a1 : 0.2f * a1; l1 += __expf(a1);
            float a2 = as4.z + ad4.z; a2 = a2 > 0.f ? a2 : 0.2f * a2; l2 += __expf(a2);
            float a3 = as4.w + ad4.w; a3 = a3 > 0.f ? a3 : 0.2f * a3; l3 += __expf(a3);
        }
        l0 = wave_sum(l0); l1 = wave_sum(l1); l2 = wave_sum(l2); l3 = wave_sum(l3);
    }
    int l31 = lane & 31, hi = lane >> 5;
    int head = l31 >> 3;
    float acc8[8] = {};
    f32x2 accF[4] = {};
    unsigned tb = (unsigned)(l31 * 16);
    const char* xwb_ = (const char*)xw;
    if (deg <= CAP) {
        int i = 0;
        for (; i + 16 <= deg; i += 16) {
            int iA = i + 8 * hi;
            int o0 = ss[w][iA], o1 = ss[w][iA + 1], o2 = ss[w][iA + 2], o3 = ss[w][iA + 3];
            int o4 = ss[w][iA + 4], o5 = ss[w][iA + 5], o6 = ss[w][iA + 6], o7 = ss[w][iA + 7];
            float e0 = ea_s[w][iA][head],     e1 = ea_s[w][iA + 1][head];
            float e2 = ea_s[w][iA + 2][head], e3 = ea_s[w][iA + 3][head];
            float e4 = ea_s[w][iA + 4][head], e5 = ea_s[w][iA + 5][head];
            float e6 = ea_s[w][iA + 6][head], e7 = ea_s[w][iA + 7][head];
            uint4 v0 = *(const uint4*)(xwb_ + ((unsigned)o0 + tb));
            uint4 v1 = *(const uint4*)(xwb_ + ((unsigned)o1 + tb));
            uint4 v2 = *(const uint4*)(xwb_ + ((unsigned)o2 + tb));
            uint4 v3 = *(const uint4*)(xwb_ + ((unsigned)o3 + tb));
            uint4 v4 = *(const uint4*)(xwb_ + ((unsigned)o4 + tb));
            uint4 v5 = *(const uint4*)(xwb_ + ((unsigned)o5 + tb));
            uint4 v6 = *(const uint4*)(xwb_ + ((unsigned)o6 + tb));
            uint4 v7 = *(const uint4*)(xwb_ + ((unsigned)o7 + tb));
            unsigned p01, p23, p45, p67;
            asm("v_cvt_pk_bf16_f32 %0, %1, %2" : "=v"(p01) : "v"(e0), "v"(e1));
            asm("v_cvt_pk_bf16_f32 %0, %1, %2" : "=v"(p23) : "v"(e2), "v"(e3));
            asm("v_cvt_pk_bf16_f32 %0, %1, %2" : "=v"(p45) : "v"(e4), "v"(e5));
            asm("v_cvt_pk_bf16_f32 %0, %1, %2" : "=v"(p67) : "v"(e6), "v"(e7));
            dot8x2(v0, v1, p01, acc8);
            dot8x2(v2, v3, p23, acc8);
            dot8x2(v4, v5, p45, acc8);
            dot8x2(v6, v7, p67, acc8);
        }
        for (; i + 8 <= deg; i += 8) {
            int iA = i + 4 * hi;
            int o0 = ss[w][iA], o1 = ss[w][iA + 1], o2 = ss[w][iA + 2], o3 = ss[w][iA + 3];
            float e0 = ea_s[w][iA][head],     e1 = ea_s[w][iA + 1][head];
            float e2 = ea_s[w][iA + 2][head], e3 = ea_s[w][iA + 3][head];
            uint4 v0 = *(const uint4*)(xwb_ + ((unsigned)o0 + tb));
            uint4 v1 = *(const uint4*)(xwb_ + ((unsigned)o1 + tb));
            uint4 v2 = *(const uint4*)(xwb_ + ((unsigned)o2 + tb));
            uint4 v3 = *(const uint4*)(xwb_ + ((unsigned)o3 + tb));
            unsigned p01, p23;
            asm("v_cvt_pk_bf16_f32 %0, %1, %2" : "=v"(p01) : "v"(e0), "v"(e1));
            asm("v_cvt_pk_bf16_f32 %0, %1, %2" : "=v"(p23) : "v"(e2), "v"(e3));
            dot8x2(v0, v1, p01, acc8);
            dot8x2(v2, v3, p23, acc8);
        }
        for (; i + 4 <= deg; i += 4) {
            int iA = i + 2 * hi;
            int o0 = ss[w][iA], o1 = ss[w][iA + 1];
            float e0 = ea_s[w][iA][head], e1 = ea_s[w][iA + 1][head];
            unsigned pe;
            asm("v_cvt_pk_bf16_f32 %0, %1, %2" : "=v"(pe) : "v"(e0), "v"(e1));
            uint4 v0 = *(const uint4*)(xwb_ + ((unsigned)o0 + tb));
            uint4 v1 = *(const uint4*)(xwb_ + ((unsigned)o1 + tb));
            dot8x2(v0, v1, pe, acc8);
        }
        if (i < deg) {
            int iA = i + 2 * hi, iB = iA + 1;
            bool okA = iA < deg, okB = iB < deg;
            int ia = okA ? iA : 0;
            int ib = okB ? iB : 0;
            int o0 = ss[w][ia], o1 = ss[w][ib];
            float e0 = okA ? ea_s[w][ia][head] : 0.f;
            float e1 = okB ? ea_s[w][ib][head] : 0.f;
            unsigned pe;
            asm("v_cvt_pk_bf16_f32 %0, %1, %2" : "=v"(pe) : "v"(e0), "v"(e1));
            uint4 v0 = *(const uint4*)(xwb_ + ((unsigned)o0 + tb));
            uint4 v1 = *(const uint4*)(xwb_ + ((unsigned)o1 + tb));
            dot8x2(v0, v1, pe, acc8);
        }
    } else {
        const unsigned short* xwc = xw + l31 * 8;
        float adh = head == 0 ? ad4.x : head == 1 ? ad4.y : head == 2 ? ad4.z : ad4.w;
        for (int i = beg; i < end; i += 2) {
            int idx = i + hi;
            bool ok = idx < end;
            int sA = csr[ok ? idx : beg];
            float a = aS[sA * 4 + head] + adh;
            a = a > 0.f ? a : 0.2f * a;
            float eA = ok ? __expf(a) : 0.f;
            uint4 vA = *(const uint4*)(xwc + (size_t)sA * HC);
            f32x2 eA2; eA2.x = eA; eA2.y = eA;
            fma8pk(vA, eA2, accF);
        }
    }
    float r8[8];
#pragma unroll
    for (int j = 0; j < 8; j++) {
        float v = acc8[j] + accF[j >> 1][j & 1];
        v += __shfl_xor(v, 32);
        r8[j] = v;
    }
    if (hi == 0) {
        float ilh;
        if (deg <= CAP) {
            float lsum = 0.f;
            for (int j = (l31 & 7); j < deg; j += 8) lsum += ea_s[w][j][head];
            lsum += __shfl_xor(lsum, 1);
            lsum += __shfl_xor(lsum, 2);
            lsum += __shfl_xor(lsum, 4);
            ilh = 1.0f / (lsum + 1e-16f);
        } else {
            float lh = head == 0 ? l0 : head == 1 ? l1 : head == 2 ? l2 : l3;
            ilh = 1.0f / (lh + 1e-16f);
        }
        float4 b0 = *(const float4*)(bias + l31 * 8);
        float4 b1 = *(const float4*)(bias + l31 * 8 + 4);
        float r[8];
        r[0] = r8[0] * ilh + b0.x;
        r[1] = r8[1] * ilh + b0.y;
        r[2] = r8[2] * ilh + b0.z;
        r[3] = r8[3] * ilh + b0.w;
        r[4] = r8[4] * ilh + b1.x;
        r[5] = r8[5] * ilh + b1.y;
        r[6] = r8[6] * ilh + b1.z;
        r[7] = r8[7] * ilh + b1.w;
#pragma unroll
        for (int j = 0; j < 8; j++) r[j] = r[j] > 0.f ? r[j] : expm1f(r[j]);
        if (hout) {
            uint4 o;
            o.x = (unsigned)f2bf(r[0]) | ((unsigned)f2bf(r[1]) << 16);
            o.y = (unsigned)f2bf(r[2]) | ((unsigned)f2bf(r[3]) << 16);
            o.z = (unsigned)f2bf(r[4]) | ((unsigned)f2bf(r[5]) << 16);
            o.w = (unsigned)f2bf(r[6]) | ((unsigned)f2bf(r[7]) << 16);
            *(uint4*)(hout + (size_t)n * HC + l31 * 8) = o;
        }
        float4 w0 = *(const float4*)(poolw + l31 * 8);
        float4 w1v = *(const float4*)(poolw + l31 * 8 + 4);
        float p = r[0] * w0.x + r[1] * w0.y + r[2] * w0.z + r[3] * w0.w +
                  r[4] * w1v.x + r[5] * w1v.y + r[6] * w1v.z + r[7] * w1v.w;
        for (int o = 16; o; o >>= 1) p += __shfl_xor(p, o);
        if (l31 == 0) { float v = p + poolb[0]; xpre[n] = v; pshare[w] = v; }
    }
    // R18: block-level LN-stats accumulation (2 atomics/block to 32 addresses)
    __syncthreads();
    if (t == 0) {
        float su = 0.f, sq = 0.f;
#pragma unroll
        for (int j = 0; j < 4; j++) { float v = pshare[j]; su += v; sq += v * v; }
        int row = blockIdx.x >> 9;
        atomicAdd(&stats[row * 2], su);
        atomicAdd(&stats[row * 2 + 1], sq);
    }
}

// ================== R18: 4-dispatch head (no grid sync, no reduce kernels) ==================

// enc0 split-K with LN applied on the fly (replaces ln3 + splitk0).
// grid (4, 96); KC=64; K=3*NN; Nc=FC0.
__global__ __launch_bounds__(256) void k_fc0(
    const float* __restrict__ xmean, const float* __restrict__ x1pre, const float* __restrict__ x2pre,
    const float* __restrict__ stats0, const float* __restrict__ stats1, const float* __restrict__ stats2,
    const float* __restrict__ lw, const float* __restrict__ lb,
    const float* __restrict__ W, float* __restrict__ partial) {
    __shared__ float in_s[16][64];
    __shared__ float murs[16][2];
    int t = threadIdx.x;
    int bx = blockIdx.x, by = blockIdx.y;
    int k0 = by * 64;
    int seg = k0 >> 11;          // 0,1,2
    int c0 = k0 & (NN - 1);
    const float* src = seg == 0 ? xmean : seg == 1 ? x1pre : x2pre;
    const float* st  = seg == 0 ? stats0 : seg == 1 ? stats1 : stats2;
    if (t < 16) {
        float su = st[t * 2], sq = st[t * 2 + 1];
        float mu = su * (1.0f / NN);
        float var = sq * (1.0f / NN) - mu * mu;
        murs[t][0] = mu;
        murs[t][1] = rsqrtf(var + 1e-5f);
    }
    __syncthreads();
#pragma unroll
    for (int j = 0; j < 4; j++) {
        int idx = t + j * 256;
        int r = idx >> 6, kk = idx & 63;
        int c = c0 + kk;
        float xv = src[(size_t)r * NN + c];
        in_s[r][kk] = (xv - murs[r][0]) * murs[r][1] * lw[c] + lb[c];
    }
    __syncthreads();
    int col = bx * 256 + t;
    float acc[16] = {};
    for (int kk = 0; kk < 64; kk++) {
        float wv = W[(size_t)(k0 + kk) * FC0 + col];
#pragma unroll
        for (int r = 0; r < 16; r++) acc[r] += in_s[r][kk] * wv;
    }
    float* pp = partial + ((size_t)by * 16) * FC0 + col;
#pragma unroll
    for (int r = 0; r < 16; r++) pp[(size_t)r * FC0] = acc[r];
}

// enc1 split-K; recomputes its e0 slice from part0 (+bias+ELU). grid (2, 64); KC=16.
__global__ __launch_bounds__(256) void k_fc1(
    const float* __restrict__ part0, const float* __restrict__ b0,
    const float* __restrict__ W, float* __restrict__ partial) {
    __shared__ float in_s[16][16];
    int t = threadIdx.x;
    int bx = blockIdx.x, by = blockIdx.y;
    int k0 = by * 16;
    {
        int r = t >> 4, kk = t & 15;
        float s = 0.f;
#pragma unroll 8
        for (int k = 0; k < 96; k++) s += part0[((size_t)(k * 16) + r) * FC0 + (k0 + kk)];
        s += b0[k0 + kk];
        in_s[r][kk] = s > 0.f ? s : expm1f(s);
    }
    __syncthreads();
    int col = bx * 256 + t;
    float acc[16] = {};
#pragma unroll
    for (int kk = 0; kk < 16; kk++) {
        float wv = W[(size_t)(k0 + kk) * FC1 + col];
#pragma unroll
        for (int r = 0; r < 16; r++) acc[r] += in_s[r][kk] * wv;
    }
    float* pp = partial + ((size_t)by * 16) * FC1 + col;
#pragma unroll
    for (int r = 0; r < 16; r++) pp[(size_t)r * FC1] = acc[r];
}

// enc2 split-K; recomputes its e1 slice from part1. grid (32); KC=16; Nc=128.
__global__ __launch_bounds__(256) void k_fc2(
    const float* __restrict__ part1, const float* __restrict__ b1,
    const float* __restrict__ W, float* __restrict__ partial) {
    __shared__ float in_s[16][16];
    int t = threadIdx.x;
    int by = blockIdx.x;
    int k0 = by * 16;
    {
        int r = t >> 4, kk = t & 15;
        float s = 0.f;
#pragma unroll 8
        for (int k = 0; k < 64; k++) s += part1[((size_t)(k * 16) + r) * FC1 + (k0 + kk)];
        s += b1[k0 + kk];
        in_s[r][kk] = s > 0.f ? s : expm1f(s);
    }
    __syncthreads();
    if (t < OMIC) {
        int col = t;
        float acc[16] = {};
#pragma unroll
        for (int kk = 0; kk < 16; kk++) {
            float wv = W[(size_t)(k0 + kk) * OMIC + col];
#pragma unroll
            for (int r = 0; r < 16; r++) acc[r] += in_s[r][kk] * wv;
        }
        float* pp = partial + ((size_t)by * 16) * OMIC + col;
#pragma unroll
        for (int r = 0; r < 16; r++) pp[(size_t)r * OMIC] = acc[r];
    }
}

// last layer; recomputes e2 from part2 in-block. 1 block.
__global__ __launch_bounds__(256) void k_last2(
    const float* __restrict__ part2, const float* __restrict__ b2,
    const float* __restrict__ W, const float* __restrict__ bl, float* __restrict__ Out) {
    __shared__ float e2s[16][OMIC];
    int t = threadIdx.x;
    for (int idx = t; idx < 16 * OMIC; idx += 256) {
        int r = idx >> 7, c = idx & 127;
        float s = 0.f;
#pragma unroll 8
        for (int k = 0; k < 32; k++) s += part2[((size_t)(k * 16) + r) * OMIC + c];
        s += b2[c];
        e2s[r][c] = s > 0.f ? s : expm1f(s);
    }
    __syncthreads();
    int r = t >> 4, c = (t >> 3) & 1, ksub = t & 7;
    float s = 0.f;
#pragma unroll
    for (int k = 0; k < OMIC / 8; k++) s += e2s[r][k * 8 + ksub] * W[(k * 8 + ksub) * OUTD + c];
    for (int o = 1; o < 8; o <<= 1) s += __shfl_xor(s, o);
    if (ksub == 0) Out[r * OUTD + c] = s + bl[c];
}

extern "C" void kernel_launch(void* const* d_in, const int* in_sizes, int n_in,
                              void* d_out, int out_size, void* d_ws, size_t ws_size,
                              hipStream_t stream) {
    (void)in_sizes; (void)n_in; (void)out_size; (void)ws_size;
    const float* x        = (const float*)d_in[0];
    const int*   ei       = (const int*)d_in[1];
    const float* w1       = (const float*)d_in[2];
    const float* att_src1 = (const float*)d_in[3];
    const float* att_dst1 = (const float*)d_in[4];
    const float* bias1    = (const float*)d_in[5];
    const float* pool1_w  = (const float*)d_in[6];
    const float* pool1_b  = (const float*)d_in[7];
    const float* w2       = (const float*)d_in[8];
    const float* att_src2 = (const float*)d_in[9];
    const float* att_dst2 = (const float*)d_in[10];
    const float* bias2    = (const float*)d_in[11];
    const float* pool2_w  = (const float*)d_in[12];
    const float* pool2_b  = (const float*)d_in[13];
    const float* ln_w     = (const float*)d_in[14];
    const float* ln_b     = (const float*)d_in[15];
    const float* enc0_w   = (const float*)d_in[16];
    const float* enc0_b   = (const float*)d_in[17];
    const float* enc1_w   = (const float*)d_in[18];
    const float* enc1_b   = (const float*)d_in[19];
    const float* enc2_w   = (const float*)d_in[20];
    const float* enc2_b   = (const float*)d_in[21];
    const float* last_w   = (const float*)d_in[22];
    const float* last_b   = (const float*)d_in[23];
    float* out = (float*)d_out;

    char* p = (char*)d_ws;
    auto alloc = [&](size_t bytes) -> void* {
        void* r = (void*)p;
        p += (bytes + 255) & ~(size_t)255;
        return r;
    };
    unsigned short* xwb  = (unsigned short*)alloc((size_t)NTN * HC * 2);
    unsigned short* hb   = (unsigned short*)alloc((size_t)NTN * HC * 2);
    unsigned short* xb   = (unsigned short*)alloc((size_t)NTN * IN_CH * 2);
    unsigned short* w1t  = (unsigned short*)alloc((size_t)HC * IN_CH * 2);
    unsigned short* w2t  = (unsigned short*)alloc((size_t)HC * HC * 2);
    float* a_src  = (float*)alloc((size_t)NTN * 4 * 4);
    float* a_dst  = (float*)alloc((size_t)NTN * 4 * 4);
    float* xmean  = (float*)alloc((size_t)NTN * 4);
    float* x1pre  = (float*)alloc((size_t)NTN * 4);
    float* x2pre  = (float*)alloc((size_t)NTN * 4);
    float* part0  = (float*)alloc((size_t)96 * 16 * FC0 * 4);
    float* part1  = (float*)alloc((size_t)64 * 16 * FC1 * 4);
    float* part2  = (float*)alloc((size_t)32 * 16 * OMIC * 4);
    // deg followed by 3x32-float LN stats; single memset covers both
    int*   deg    = (int*)alloc((size_t)NTN * 4 + 384);
    float* stats0 = (float*)(deg + NTN);
    float* stats1 = stats0 + 32;
    float* stats2 = stats0 + 64;
    int*   rowptr = (int*)alloc((size_t)(NTN + 1) * 4);
    int*   epos   = (int*)alloc((size_t)EREAL * 4);
    int*   csr    = (int*)alloc((size_t)ETOT * 4);

    hipMemsetAsync(deg, 0, (size_t)NTN * 4 + 384, stream);

    k_pre<<<PREP_BLKS + DEG_BLKS + CASTW_BLKS, 256, 0, stream>>>(
        x, xb, xmean, ei, deg, epos, w1, w2, w1t, w2t, stats0);
    k_scan<<<1, 1024, 0, stream>>>(deg, rowptr, csr);

    // GAT layer 1 (+ fused CSR fill blocks)
    k_gemm_mfma<<<dim3(4, GEMM_YB + FILL_YB), 256, 0, stream>>>(
        xb, w1t, IN_CH, att_src1, att_dst1, xwb, a_src, a_dst, ei, epos, rowptr, csr);
    k_agg<<<NTN / 4, 256, 0, stream>>>(xwb, a_src, a_dst, rowptr, csr, bias1, pool1_w, pool1_b, hb, x1pre, stats1);

    // GAT layer 2
    k_gemm_mfma<<<dim3(4, GEMM_YB), 256, 0, stream>>>(
        hb, w2t, HC, att_src2, att_dst2, xwb, a_src, a_dst, ei, epos, rowptr, csr);
    k_agg<<<NTN / 4, 256, 0, stream>>>(xwb, a_src, a_dst, rowptr, csr, bias2, pool2_w, pool2_b, (unsigned short*)nullptr, x2pre, stats2);

    // R18 head: 4 ordinary dispatches (LN fused into fc0; reduces fused into consumers)
    k_fc0<<<dim3(4, 96), 256, 0, stream>>>(xmean, x1pre, x2pre, stats0, stats1, stats2,
                                           ln_w, ln_b, enc0_w, part0);
    k_fc1<<<dim3(2, 64), 256, 0, stream>>>(part0, enc0_b, enc1_w, part1);
    k_fc2<<<32, 256, 0, stream>>>(part1, enc1_b, enc2_w, part2);
    k_last2<<<1, 256, 0, stream>>>(part2, enc2_b, last_w, last_b, out);
}

// Round 8
// 338.010 us; speedup vs baseline: 2.3154x; 2.3154x over previous
//
#include <hip/hip_runtime.h>
#include <math.h>

#define NTN 32768
#define BB 16
#define NN 2048
#define IN_CH 128
#define HC 256
#define EREAL 524288
#define ETOT (EREAL + NTN)
#define FC0 1024
#define FC1 512
#define OMIC 128
#define OUTD 2
#define CAP 96

#define PREP_BLKS (NTN / 4)
#define DEG_BLKS (EREAL / 256)
#define CASTW_BLKS ((HC * IN_CH + HC * HC) / 256)
#define GEMM_YB (NTN / 128)
#define FILL_YB 512   // 512*4 blocks * 256 threads = 524288 edges

typedef __attribute__((ext_vector_type(8))) short bf16x8;
typedef __attribute__((ext_vector_type(4))) float f32x4;
typedef __attribute__((ext_vector_type(2))) float f32x2;

static __device__ __forceinline__ float wave_sum(float v) {
    for (int o = 32; o; o >>= 1) v += __shfl_xor(v, o);
    return v;
}
static __device__ __forceinline__ unsigned short f2bf(float f) {
    unsigned u = __float_as_uint(f);
    unsigned r = (u + 0x7fff + ((u >> 16) & 1)) >> 16;
    return (unsigned short)r;
}
// R16: wave-local LDS producer->consumer fence
static __device__ __forceinline__ void wave_sync() {
    asm volatile("s_waitcnt lgkmcnt(0)" ::: "memory");
    __builtin_amdgcn_sched_barrier(0);
}
static __device__ __forceinline__ void pkfma(f32x2& acc, f32x2 ab, f32x2 e2) {
    asm("v_pk_fma_f32 %0, %1, %2, %0" : "+v"(acc) : "v"(ab), "v"(e2));
}
static __device__ __forceinline__ void fma8pk(uint4 v, f32x2 e2, f32x2* acc) {
    f32x2 p;
    p.x = __uint_as_float(v.x << 16); p.y = __uint_as_float(v.x & 0xffff0000u);
    pkfma(acc[0], p, e2);
    p.x = __uint_as_float(v.y << 16); p.y = __uint_as_float(v.y & 0xffff0000u);
    pkfma(acc[1], p, e2);
    p.x = __uint_as_float(v.z << 16); p.y = __uint_as_float(v.z & 0xffff0000u);
    pkfma(acc[2], p, e2);
    p.x = __uint_as_float(v.w << 16); p.y = __uint_as_float(v.w & 0xffff0000u);
    pkfma(acc[3], p, e2);
}
// R14: bf16 dot2 hot loop (v_perm pair-build + v_dot2_f32_bf16)
static __device__ __forceinline__ void dot2bf(float& acc, unsigned px, unsigned pe) {
    asm("v_dot2_f32_bf16 %0, %1, %2, %0" : "+v"(acc) : "v"(px), "v"(pe));
}
static __device__ __forceinline__ void dot8x2(uint4 a, uint4 b, unsigned pe, float* acc) {
    unsigned p;
    p = __builtin_amdgcn_perm(a.x, b.x, 0x01000504u); dot2bf(acc[0], p, pe);
    p = __builtin_amdgcn_perm(a.x, b.x, 0x03020706u); dot2bf(acc[1], p, pe);
    p = __builtin_amdgcn_perm(a.y, b.y, 0x01000504u); dot2bf(acc[2], p, pe);
    p = __builtin_amdgcn_perm(a.y, b.y, 0x03020706u); dot2bf(acc[3], p, pe);
    p = __builtin_amdgcn_perm(a.z, b.z, 0x01000504u); dot2bf(acc[4], p, pe);
    p = __builtin_amdgcn_perm(a.z, b.z, 0x03020706u); dot2bf(acc[5], p, pe);
    p = __builtin_amdgcn_perm(a.w, b.w, 0x01000504u); dot2bf(acc[6], p, pe);
    p = __builtin_amdgcn_perm(a.w, b.w, 0x03020706u); dot2bf(acc[7], p, pe);
}

// ---- fused: x->bf16 + mean | deg count + edge slot | weight transpose-casts ----
__global__ __launch_bounds__(256) void k_pre(
    const float* __restrict__ x, unsigned short* __restrict__ xb, float* __restrict__ xmean,
    const int* __restrict__ ei, int* __restrict__ deg, int* __restrict__ epos,
    const float* __restrict__ w1, const float* __restrict__ w2,
    unsigned short* __restrict__ w1t, unsigned short* __restrict__ w2t) {
    int b = blockIdx.x, t = threadIdx.x;
    if (b < PREP_BLKS) {
        int wave = t >> 6, lane = t & 63;
        int n = b * 4 + wave;
        float2 v = *(const float2*)(x + (size_t)n * IN_CH + lane * 2);
        ushort2 o;
        o.x = f2bf(v.x); o.y = f2bf(v.y);
        *(ushort2*)(xb + (size_t)n * IN_CH + lane * 2) = o;
        float s = wave_sum(v.x + v.y);
        if (lane == 0) xmean[n] = s * (1.0f / 128.0f);
    } else if (b < PREP_BLKS + DEG_BLKS) {
        int e = (b - PREP_BLKS) * 256 + t;
        int d = ei[EREAL + e];
        epos[e] = atomicAdd(&deg[d], 1);
    } else {
        int idx = (b - PREP_BLKS - DEG_BLKS) * 256 + t;
        if (idx < HC * IN_CH) {
            int n = idx / IN_CH, k = idx % IN_CH;
            w1t[idx] = f2bf(w1[(size_t)k * HC + n]);
        } else {
            int j = idx - HC * IN_CH;
            int n = j / HC, k = j % HC;
            w2t[j] = f2bf(w2[(size_t)k * HC + n]);
        }
    }
}

// ---- scan degrees -> rowptr; write self-loop at slot 0 of each segment ----
__global__ __launch_bounds__(1024) void k_scan(const int* __restrict__ deg, int* __restrict__ rowptr,
                                               int* __restrict__ csr) {
    __shared__ int sd[1024];
    int t = threadIdx.x;
    int base = t * 32;
    int loc[32];
    int s = 0;
#pragma unroll
    for (int j = 0; j < 32; j++) { int d = deg[base + j] + 1; loc[j] = d; s += d; }
    sd[t] = s; __syncthreads();
    for (int o = 1; o < 1024; o <<= 1) {
        int v = (t >= o) ? sd[t - o] : 0;
        __syncthreads();
        sd[t] += v;
        __syncthreads();
    }
    int run = sd[t] - s;  // exclusive prefix
#pragma unroll
    for (int j = 0; j < 32; j++) {
        rowptr[base + j] = run;
        csr[run] = base + j;   // self-loop at slot 0
        run += loc[j];
    }
    if (t == 1023) rowptr[NTN] = run;
}

// ---- bf16 MFMA GEMM (+ optional fused CSR-fill blocks at by >= GEMM_YB) ----
__global__ __launch_bounds__(256) void k_gemm_mfma(
    const unsigned short* __restrict__ A, const unsigned short* __restrict__ Bt, int K,
    const float* __restrict__ attS, const float* __restrict__ attD,
    unsigned short* __restrict__ Cout, float* __restrict__ aS, float* __restrict__ aD,
    const int* __restrict__ ei, const int* __restrict__ epos,
    const int* __restrict__ rowptr, int* __restrict__ csr) {
    __shared__ unsigned short As[128][72];
    __shared__ unsigned short Bs[64][72];
    const int t = threadIdx.x;
    const int bx = blockIdx.x, by = blockIdx.y;
    if (by >= GEMM_YB) {
        int e = (((by - GEMM_YB) * 4 + bx)) * 256 + t;
        int s = ei[e], d = ei[EREAL + e];
        csr[rowptr[d] + 1 + epos[e]] = s;
        return;
    }
    const int lane = t & 63, wave = t >> 6;
    const int quad = lane >> 4, l16 = lane & 15;
    const int arow = t >> 1, acol = (t & 1) * 32;
    const int brow = t >> 2, bcol = (t & 3) * 16;
    const unsigned short* Ag = A + (size_t)(by * 128 + arow) * K + acol;
    const unsigned short* Bg = Bt + (size_t)(bx * 64 + brow) * K + bcol;
    f32x4 acc[2][4] = {};
    for (int k0 = 0; k0 < K; k0 += 64) {
        uint4 a0 = *(const uint4*)(Ag + k0);
        uint4 a1 = *(const uint4*)(Ag + k0 + 8);
        uint4 a2 = *(const uint4*)(Ag + k0 + 16);
        uint4 a3 = *(const uint4*)(Ag + k0 + 24);
        uint4 b0 = *(const uint4*)(Bg + k0);
        uint4 b1 = *(const uint4*)(Bg + k0 + 8);
        __syncthreads();
        *(uint4*)&As[arow][acol +  0] = a0;
        *(uint4*)&As[arow][acol +  8] = a1;
        *(uint4*)&As[arow][acol + 16] = a2;
        *(uint4*)&As[arow][acol + 24] = a3;
        *(uint4*)&Bs[brow][bcol +  0] = b0;
        *(uint4*)&Bs[brow][bcol +  8] = b1;
        __syncthreads();
#pragma unroll
        for (int kc = 0; kc < 64; kc += 32) {
            bf16x8 af[2], bfr[4];
#pragma unroll
            for (int mt = 0; mt < 2; mt++)
                af[mt] = *(const bf16x8*)&As[wave * 32 + mt * 16 + l16][kc + quad * 8];
#pragma unroll
            for (int nt = 0; nt < 4; nt++)
                bfr[nt] = *(const bf16x8*)&Bs[nt * 16 + l16][kc + quad * 8];
#pragma unroll
            for (int mt = 0; mt < 2; mt++)
#pragma unroll
                for (int nt = 0; nt < 4; nt++)
                    acc[mt][nt] = __builtin_amdgcn_mfma_f32_16x16x32_bf16(af[mt], bfr[nt], acc[mt][nt], 0, 0, 0);
        }
    }
    float as_l[4], ad_l[4];
#pragma unroll
    for (int nt = 0; nt < 4; nt++) {
        int gcol = bx * 64 + nt * 16 + l16;
        as_l[nt] = attS[gcol];
        ad_l[nt] = attD[gcol];
    }
#pragma unroll
    for (int mt = 0; mt < 2; mt++) {
#pragma unroll
        for (int reg = 0; reg < 4; reg++) {
            int grow = by * 128 + wave * 32 + mt * 16 + quad * 4 + reg;
            float ps = 0.f, pd = 0.f;
#pragma unroll
            for (int nt = 0; nt < 4; nt++) {
                float v = acc[mt][nt][reg];
                Cout[(size_t)grow * HC + bx * 64 + nt * 16 + l16] = f2bf(v);
                ps += v * as_l[nt];
                pd += v * ad_l[nt];
            }
            for (int o = 8; o; o >>= 1) { ps += __shfl_xor(ps, o); pd += __shfl_xor(pd, o); }
            if (l16 == 0) { aS[grow * 4 + bx] = ps; aD[grow * 4 + bx] = pd; }
        }
    }
}

// ---- attention aggregate (R16: 1 wave = 1 node; waves retire independently) ----
__global__ __launch_bounds__(256) void k_agg(
    const unsigned short* __restrict__ xw, const float* __restrict__ aS, const float* __restrict__ aD,
    const int* __restrict__ rowptr, const int* __restrict__ csr,
    const float* __restrict__ bias, const float* __restrict__ poolw, const float* __restrict__ poolb,
    unsigned short* __restrict__ hout, float* __restrict__ xpre) {
    __shared__ float ea_s[4][CAP][4];
    __shared__ int   ss[4][CAP];       // row byte offsets (s * HC * 2)
    int t = threadIdx.x;
    int w = t >> 6, lane = t & 63;
    int n = blockIdx.x * 4 + w;
    int beg = rowptr[n], end = rowptr[n + 1];
    int deg = end - beg;
    float4 ad4 = *(const float4*)(aD + n * 4);
    float l0 = 0.f, l1 = 0.f, l2 = 0.f, l3 = 0.f;
    if (deg <= CAP) {
        for (int i = lane; i < deg; i += 64) {
            int s = csr[beg + i];
            ss[w][i] = s << 9;
            float4 as4 = *(const float4*)(aS + s * 4);
            float a0 = as4.x + ad4.x; a0 = a0 > 0.f ? a0 : 0.2f * a0;
            float a1 = as4.y + ad4.y; a1 = a1 > 0.f ? a1 : 0.2f * a1;
            float a2 = as4.z + ad4.z; a2 = a2 > 0.f ? a2 : 0.2f * a2;
            float a3 = as4.w + ad4.w; a3 = a3 > 0.f ? a3 : 0.2f * a3;
            float4 e4;
            e4.x = __expf(a0); e4.y = __expf(a1); e4.z = __expf(a2); e4.w = __expf(a3);
            *(float4*)&ea_s[w][i][0] = e4;
        }
        wave_sync();
    } else {
        for (int i = lane; i < deg; i += 64) {
            int s = csr[beg + i];
            float4 as4 = *(const float4*)(aS + s * 4);
            float a0 = as4.x + ad4.x; a0 = a0 > 0.f ? a0 : 0.2f * a0; l0 += __expf(a0);
            float a1 = as4.y + ad4.y; a1 = a1 > 0.f ? a1 : 0.2f * a1; l1 += __expf(a1);
            float a2 = as4.z + ad4.z; a2 = a2 > 0.f ? a2 : 0.2f * a2; l2 += __expf(a2);
            float a3 = as4.w + ad4.w; a3 = a3 > 0.f ? a3 : 0.2f * a3; l3 += __expf(a3);
        }
        l0 = wave_sum(l0); l1 = wave_sum(l1); l2 = wave_sum(l2); l3 = wave_sum(l3);
    }
    int l31 = lane & 31, hi = lane >> 5;
    int head = l31 >> 3;
    float acc8[8] = {};
    f32x2 accF[4] = {};
    unsigned tb = (unsigned)(l31 * 16);
    const char* xwb_ = (const char*)xw;
    if (deg <= CAP) {
        int i = 0;
        for (; i + 16 <= deg; i += 16) {
            int iA = i + 8 * hi;
            int o0 = ss[w][iA], o1 = ss[w][iA + 1], o2 = ss[w][iA + 2], o3 = ss[w][iA + 3];
            int o4 = ss[w][iA + 4], o5 = ss[w][iA + 5], o6 = ss[w][iA + 6], o7 = ss[w][iA + 7];
            float e0 = ea_s[w][iA][head],     e1 = ea_s[w][iA + 1][head];
            float e2 = ea_s[w][iA + 2][head], e3 = ea_s[w][iA + 3][head];
            float e4 = ea_s[w][iA + 4][head], e5 = ea_s[w][iA + 5][head];
            float e6 = ea_s[w][iA + 6][head], e7 = ea_s[w][iA + 7][head];
            uint4 v0 = *(const uint4*)(xwb_ + ((unsigned)o0 + tb));
            uint4 v1 = *(const uint4*)(xwb_ + ((unsigned)o1 + tb));
            uint4 v2 = *(const uint4*)(xwb_ + ((unsigned)o2 + tb));
            uint4 v3 = *(const uint4*)(xwb_ + ((unsigned)o3 + tb));
            uint4 v4 = *(const uint4*)(xwb_ + ((unsigned)o4 + tb));
            uint4 v5 = *(const uint4*)(xwb_ + ((unsigned)o5 + tb));
            uint4 v6 = *(const uint4*)(xwb_ + ((unsigned)o6 + tb));
            uint4 v7 = *(const uint4*)(xwb_ + ((unsigned)o7 + tb));
            unsigned p01, p23, p45, p67;
            asm("v_cvt_pk_bf16_f32 %0, %1, %2" : "=v"(p01) : "v"(e0), "v"(e1));
            asm("v_cvt_pk_bf16_f32 %0, %1, %2" : "=v"(p23) : "v"(e2), "v"(e3));
            asm("v_cvt_pk_bf16_f32 %0, %1, %2" : "=v"(p45) : "v"(e4), "v"(e5));
            asm("v_cvt_pk_bf16_f32 %0, %1, %2" : "=v"(p67) : "v"(e6), "v"(e7));
            dot8x2(v0, v1, p01, acc8);
            dot8x2(v2, v3, p23, acc8);
            dot8x2(v4, v5, p45, acc8);
            dot8x2(v6, v7, p67, acc8);
        }
        for (; i + 8 <= deg; i += 8) {
            int iA = i + 4 * hi;
            int o0 = ss[w][iA], o1 = ss[w][iA + 1], o2 = ss[w][iA + 2], o3 = ss[w][iA + 3];
            float e0 = ea_s[w][iA][head],     e1 = ea_s[w][iA + 1][head];
            float e2 = ea_s[w][iA + 2][head], e3 = ea_s[w][iA + 3][head];
            uint4 v0 = *(const uint4*)(xwb_ + ((unsigned)o0 + tb));
            uint4 v1 = *(const uint4*)(xwb_ + ((unsigned)o1 + tb));
            uint4 v2 = *(const uint4*)(xwb_ + ((unsigned)o2 + tb));
            uint4 v3 = *(const uint4*)(xwb_ + ((unsigned)o3 + tb));
            unsigned p01, p23;
            asm("v_cvt_pk_bf16_f32 %0, %1, %2" : "=v"(p01) : "v"(e0), "v"(e1));
            asm("v_cvt_pk_bf16_f32 %0, %1, %2" : "=v"(p23) : "v"(e2), "v"(e3));
            dot8x2(v0, v1, p01, acc8);
            dot8x2(v2, v3, p23, acc8);
        }
        for (; i + 4 <= deg; i += 4) {
            int iA = i + 2 * hi;
            int o0 = ss[w][iA], o1 = ss[w][iA + 1];
            float e0 = ea_s[w][iA][head], e1 = ea_s[w][iA + 1][head];
            unsigned pe;
            asm("v_cvt_pk_bf16_f32 %0, %1, %2" : "=v"(pe) : "v"(e0), "v"(e1));
            uint4 v0 = *(const uint4*)(xwb_ + ((unsigned)o0 + tb));
            uint4 v1 = *(const uint4*)(xwb_ + ((unsigned)o1 + tb));
            dot8x2(v0, v1, pe, acc8);
        }
        if (i < deg) {
            int iA = i + 2 * hi, iB = iA + 1;
            bool okA = iA < deg, okB = iB < deg;
            int ia = okA ? iA : 0;
            int ib = okB ? iB : 0;
            int o0 = ss[w][ia], o1 = ss[w][ib];
            float e0 = okA ? ea_s[w][ia][head] : 0.f;
            float e1 = okB ? ea_s[w][ib][head] : 0.f;
            unsigned pe;
            asm("v_cvt_pk_bf16_f32 %0, %1, %2" : "=v"(pe) : "v"(e0), "v"(e1));
            uint4 v0 = *(const uint4*)(xwb_ + ((unsigned)o0 + tb));
            uint4 v1 = *(const uint4*)(xwb_ + ((unsigned)o1 + tb));
            dot8x2(v0, v1, pe, acc8);
        }
    } else {
        const unsigned short* xwc = xw + l31 * 8;
        float adh = head == 0 ? ad4.x : head == 1 ? ad4.y : head == 2 ? ad4.z : ad4.w;
        for (int i = beg; i < end; i += 2) {
            int idx = i + hi;
            bool ok = idx < end;
            int sA = csr[ok ? idx : beg];
            float a = aS[sA * 4 + head] + adh;
            a = a > 0.f ? a : 0.2f * a;
            float eA = ok ? __expf(a) : 0.f;
            uint4 vA = *(const uint4*)(xwc + (size_t)sA * HC);
            f32x2 eA2; eA2.x = eA; eA2.y = eA;
            fma8pk(vA, eA2, accF);
        }
    }
    float r8[8];
#pragma unroll
    for (int j = 0; j < 8; j++) {
        float v = acc8[j] + accF[j >> 1][j & 1];
        v += __shfl_xor(v, 32);
        r8[j] = v;
    }
    if (hi == 0) {
        float ilh;
        if (deg <= CAP) {
            float lsum = 0.f;
            for (int j = (l31 & 7); j < deg; j += 8) lsum += ea_s[w][j][head];
            lsum += __shfl_xor(lsum, 1);
            lsum += __shfl_xor(lsum, 2);
            lsum += __shfl_xor(lsum, 4);
            ilh = 1.0f / (lsum + 1e-16f);
        } else {
            float lh = head == 0 ? l0 : head == 1 ? l1 : head == 2 ? l2 : l3;
            ilh = 1.0f / (lh + 1e-16f);
        }
        float4 b0 = *(const float4*)(bias + l31 * 8);
        float4 b1 = *(const float4*)(bias + l31 * 8 + 4);
        float r[8];
        r[0] = r8[0] * ilh + b0.x;
        r[1] = r8[1] * ilh + b0.y;
        r[2] = r8[2] * ilh + b0.z;
        r[3] = r8[3] * ilh + b0.w;
        r[4] = r8[4] * ilh + b1.x;
        r[5] = r8[5] * ilh + b1.y;
        r[6] = r8[6] * ilh + b1.z;
        r[7] = r8[7] * ilh + b1.w;
#pragma unroll
        for (int j = 0; j < 8; j++) r[j] = r[j] > 0.f ? r[j] : expm1f(r[j]);
        if (hout) {
            uint4 o;
            o.x = (unsigned)f2bf(r[0]) | ((unsigned)f2bf(r[1]) << 16);
            o.y = (unsigned)f2bf(r[2]) | ((unsigned)f2bf(r[3]) << 16);
            o.z = (unsigned)f2bf(r[4]) | ((unsigned)f2bf(r[5]) << 16);
            o.w = (unsigned)f2bf(r[6]) | ((unsigned)f2bf(r[7]) << 16);
            *(uint4*)(hout + (size_t)n * HC + l31 * 8) = o;
        }
        float4 w0 = *(const float4*)(poolw + l31 * 8);
        float4 w1v = *(const float4*)(poolw + l31 * 8 + 4);
        float p = r[0] * w0.x + r[1] * w0.y + r[2] * w0.z + r[3] * w0.w +
                  r[4] * w1v.x + r[5] * w1v.y + r[6] * w1v.z + r[7] * w1v.w;
        for (int o = 16; o; o >>= 1) p += __shfl_xor(p, o);
        if (l31 == 0) xpre[n] = p + poolb[0];
    }
}

// ================== R20 head: 4 dispatches, no atomics, no grid sync ==================

// enc0 split-K with LN applied on the fly; LN stats recomputed IN-BLOCK from the
// seg's 16x2048 array (128 KB, L2-resident). grid (4, 96); KC=64.
// R20 fix: LN affine indexed by position WITHIN segment (lw/lb are length-NN).
__global__ __launch_bounds__(256) void k_fc0(
    const float* __restrict__ xmean, const float* __restrict__ x1pre, const float* __restrict__ x2pre,
    const float* __restrict__ lw, const float* __restrict__ lb,
    const float* __restrict__ W, float* __restrict__ partial) {
    __shared__ float in_s[16][64];
    __shared__ float murs[16][2];
    int t = threadIdx.x;
    int bx = blockIdx.x, by = blockIdx.y;
    int k0 = by * 64;
    int seg = k0 >> 11;          // 0,1,2
    int c0 = k0 & (NN - 1);
    const float* src = seg == 0 ? xmean : seg == 1 ? x1pre : x2pre;
    // in-block LN stats: 16 lanes per row, float4 strided
    {
        int r = t >> 4, c = (t & 15) * 4;
        const float* rp = src + (size_t)r * NN;
        float su = 0.f, sq = 0.f;
        for (int j = 0; j < NN; j += 64) {
            float4 v = *(const float4*)(rp + c + j);
            su += v.x + v.y + v.z + v.w;
            sq += v.x * v.x + v.y * v.y + v.z * v.z + v.w * v.w;
        }
        for (int o = 1; o < 16; o <<= 1) { su += __shfl_xor(su, o); sq += __shfl_xor(sq, o); }
        if ((t & 15) == 0) {
            float mu = su * (1.0f / NN);
            float var = sq * (1.0f / NN) - mu * mu;
            murs[r][0] = mu;
            murs[r][1] = rsqrtf(var + 1e-5f);
        }
    }
    __syncthreads();
#pragma unroll
    for (int j = 0; j < 4; j++) {
        int idx = t + j * 256;
        int r = idx >> 6, kk = idx & 63;
        int c = c0 + kk;
        float xv = src[(size_t)r * NN + c];
        in_s[r][kk] = (xv - murs[r][0]) * murs[r][1] * lw[c] + lb[c];
    }
    __syncthreads();
    int col = bx * 256 + t;
    float acc[16] = {};
    for (int kk = 0; kk < 64; kk++) {
        float wv = W[(size_t)(k0 + kk) * FC0 + col];
#pragma unroll
        for (int r = 0; r < 16; r++) acc[r] += in_s[r][kk] * wv;
    }
    float* pp = partial + ((size_t)by * 16) * FC0 + col;
#pragma unroll
    for (int r = 0; r < 16; r++) pp[(size_t)r * FC0] = acc[r];
}

// enc1 split-K; recomputes its e0 slice from part0 (+bias+ELU). grid (2, 64); KC=16.
__global__ __launch_bounds__(256) void k_fc1(
    const float* __restrict__ part0, const float* __restrict__ b0,
    const float* __restrict__ W, float* __restrict__ partial) {
    __shared__ float in_s[16][16];
    int t = threadIdx.x;
    int bx = blockIdx.x, by = blockIdx.y;
    int k0 = by * 16;
    {
        int r = t >> 4, kk = t & 15;
        float s = 0.f;
#pragma unroll 8
        for (int k = 0; k < 96; k++) s += part0[((size_t)(k * 16) + r) * FC0 + (k0 + kk)];
        s += b0[k0 + kk];
        in_s[r][kk] = s > 0.f ? s : expm1f(s);
    }
    __syncthreads();
    int col = bx * 256 + t;
    float acc[16] = {};
#pragma unroll
    for (int kk = 0; kk < 16; kk++) {
        float wv = W[(size_t)(k0 + kk) * FC1 + col];
#pragma unroll
        for (int r = 0; r < 16; r++) acc[r] += in_s[r][kk] * wv;
    }
    float* pp = partial + ((size_t)by * 16) * FC1 + col;
#pragma unroll
    for (int r = 0; r < 16; r++) pp[(size_t)r * FC1] = acc[r];
}

// enc2 split-K; recomputes its e1 slice from part1. grid (32); KC=16; Nc=128.
__global__ __launch_bounds__(256) void k_fc2(
    const float* __restrict__ part1, const float* __restrict__ b1,
    const float* __restrict__ W, float* __restrict__ partial) {
    __shared__ float in_s[16][16];
    int t = threadIdx.x;
    int by = blockIdx.x;
    int k0 = by * 16;
    {
        int r = t >> 4, kk = t & 15;
        float s = 0.f;
#pragma unroll 8
        for (int k = 0; k < 64; k++) s += part1[((size_t)(k * 16) + r) * FC1 + (k0 + kk)];
        s += b1[k0 + kk];
        in_s[r][kk] = s > 0.f ? s : expm1f(s);
    }
    __syncthreads();
    if (t < OMIC) {
        int col = t;
        float acc[16] = {};
#pragma unroll
        for (int kk = 0; kk < 16; kk++) {
            float wv = W[(size_t)(k0 + kk) * OMIC + col];
#pragma unroll
            for (int r = 0; r < 16; r++) acc[r] += in_s[r][kk] * wv;
        }
        float* pp = partial + ((size_t)by * 16) * OMIC + col;
#pragma unroll
        for (int r = 0; r < 16; r++) pp[(size_t)r * OMIC] = acc[r];
    }
}

// last layer; recomputes e2 from part2 in-block. 1 block.
__global__ __launch_bounds__(256) void k_last2(
    const float* __restrict__ part2, const float* __restrict__ b2,
    const float* __restrict__ W, const float* __restrict__ bl, float* __restrict__ Out) {
    __shared__ float e2s[16][OMIC];
    int t = threadIdx.x;
    for (int idx = t; idx < 16 * OMIC; idx += 256) {
        int r = idx >> 7, c = idx & 127;
        float s = 0.f;
#pragma unroll 8
        for (int k = 0; k < 32; k++) s += part2[((size_t)(k * 16) + r) * OMIC + c];
        s += b2[c];
        e2s[r][c] = s > 0.f ? s : expm1f(s);
    }
    __syncthreads();
    int r = t >> 4, c = (t >> 3) & 1, ksub = t & 7;
    float s = 0.f;
#pragma unroll
    for (int k = 0; k < OMIC / 8; k++) s += e2s[r][k * 8 + ksub] * W[(k * 8 + ksub) * OUTD + c];
    for (int o = 1; o < 8; o <<= 1) s += __shfl_xor(s, o);
    if (ksub == 0) Out[r * OUTD + c] = s + bl[c];
}

extern "C" void kernel_launch(void* const* d_in, const int* in_sizes, int n_in,
                              void* d_out, int out_size, void* d_ws, size_t ws_size,
                              hipStream_t stream) {
    (void)in_sizes; (void)n_in; (void)out_size; (void)ws_size;
    const float* x        = (const float*)d_in[0];
    const int*   ei       = (const int*)d_in[1];
    const float* w1       = (const float*)d_in[2];
    const float* att_src1 = (const float*)d_in[3];
    const float* att_dst1 = (const float*)d_in[4];
    const float* bias1    = (const float*)d_in[5];
    const float* pool1_w  = (const float*)d_in[6];
    const float* pool1_b  = (const float*)d_in[7];
    const float* w2       = (const float*)d_in[8];
    const float* att_src2 = (const float*)d_in[9];
    const float* att_dst2 = (const float*)d_in[10];
    const float* bias2    = (const float*)d_in[11];
    const float* pool2_w  = (const float*)d_in[12];
    const float* pool2_b  = (const float*)d_in[13];
    const float* ln_w     = (const float*)d_in[14];
    const float* ln_b     = (const float*)d_in[15];
    const float* enc0_w   = (const float*)d_in[16];
    const float* enc0_b   = (const float*)d_in[17];
    const float* enc1_w   = (const float*)d_in[18];
    const float* enc1_b   = (const float*)d_in[19];
    const float* enc2_w   = (const float*)d_in[20];
    const float* enc2_b   = (const float*)d_in[21];
    const float* last_w   = (const float*)d_in[22];
    const float* last_b   = (const float*)d_in[23];
    float* out = (float*)d_out;

    char* p = (char*)d_ws;
    auto alloc = [&](size_t bytes) -> void* {
        void* r = (void*)p;
        p += (bytes + 255) & ~(size_t)255;
        return r;
    };
    unsigned short* xwb  = (unsigned short*)alloc((size_t)NTN * HC * 2);
    unsigned short* hb   = (unsigned short*)alloc((size_t)NTN * HC * 2);
    unsigned short* xb   = (unsigned short*)alloc((size_t)NTN * IN_CH * 2);
    unsigned short* w1t  = (unsigned short*)alloc((size_t)HC * IN_CH * 2);
    unsigned short* w2t  = (unsigned short*)alloc((size_t)HC * HC * 2);
    float* a_src  = (float*)alloc((size_t)NTN * 4 * 4);
    float* a_dst  = (float*)alloc((size_t)NTN * 4 * 4);
    float* xmean  = (float*)alloc((size_t)NTN * 4);
    float* x1pre  = (float*)alloc((size_t)NTN * 4);
    float* x2pre  = (float*)alloc((size_t)NTN * 4);
    float* part0  = (float*)alloc((size_t)96 * 16 * FC0 * 4);
    float* part1  = (float*)alloc((size_t)64 * 16 * FC1 * 4);
    float* part2  = (float*)alloc((size_t)32 * 16 * OMIC * 4);
    int*   deg    = (int*)alloc((size_t)NTN * 4);
    int*   rowptr = (int*)alloc((size_t)(NTN + 1) * 4);
    int*   epos   = (int*)alloc((size_t)EREAL * 4);
    int*   csr    = (int*)alloc((size_t)ETOT * 4);

    hipMemsetAsync(deg, 0, (size_t)NTN * 4, stream);

    k_pre<<<PREP_BLKS + DEG_BLKS + CASTW_BLKS, 256, 0, stream>>>(
        x, xb, xmean, ei, deg, epos, w1, w2, w1t, w2t);
    k_scan<<<1, 1024, 0, stream>>>(deg, rowptr, csr);

    // GAT layer 1 (+ fused CSR fill blocks)
    k_gemm_mfma<<<dim3(4, GEMM_YB + FILL_YB), 256, 0, stream>>>(
        xb, w1t, IN_CH, att_src1, att_dst1, xwb, a_src, a_dst, ei, epos, rowptr, csr);
    k_agg<<<NTN / 4, 256, 0, stream>>>(xwb, a_src, a_dst, rowptr, csr, bias1, pool1_w, pool1_b, hb, x1pre);

    // GAT layer 2
    k_gemm_mfma<<<dim3(4, GEMM_YB), 256, 0, stream>>>(
        hb, w2t, HC, att_src2, att_dst2, xwb, a_src, a_dst, ei, epos, rowptr, csr);
    k_agg<<<NTN / 4, 256, 0, stream>>>(xwb, a_src, a_dst, rowptr, csr, bias2, pool2_w, pool2_b, (unsigned short*)nullptr, x2pre);

    // R20 head: LN fused into fc0 (in-block stats recompute); reduces fused into consumers
    k_fc0<<<dim3(4, 96), 256, 0, stream>>>(xmean, x1pre, x2pre, ln_w, ln_b, enc0_w, part0);
    k_fc1<<<dim3(2, 64), 256, 0, stream>>>(part0, enc0_b, enc1_w, part1);
    k_fc2<<<32, 256, 0, stream>>>(part1, enc1_b, enc2_w, part2);
    k_last2<<<1, 256, 0, stream>>>(part2, enc2_b, last_w, last_b, out);
}

// Round 9
// 329.516 us; speedup vs baseline: 2.3751x; 1.0258x over previous
//
#include <hip/hip_runtime.h>
#include <math.h>

#define NTN 32768
#define BB 16
#define NN 2048
#define IN_CH 128
#define HC 256
#define EREAL 524288
#define ETOT (EREAL + NTN)
#define FC0 1024
#define FC1 512
#define OMIC 128
#define OUTD 2
#define CAP 96

#define PREP_BLKS (NTN / 4)
#define DEG_BLKS (EREAL / 256)
#define CASTW_BLKS ((HC * IN_CH + HC * HC) / 256)
#define GEMM_YB (NTN / 128)
#define FILL_YB 512   // 512*4 blocks * 256 threads = 524288 edges

typedef __attribute__((ext_vector_type(8))) short bf16x8;
typedef __attribute__((ext_vector_type(4))) float f32x4;
typedef __attribute__((ext_vector_type(2))) float f32x2;

static __device__ __forceinline__ float wave_sum(float v) {
    for (int o = 32; o; o >>= 1) v += __shfl_xor(v, o);
    return v;
}
static __device__ __forceinline__ unsigned short f2bf(float f) {
    unsigned u = __float_as_uint(f);
    unsigned r = (u + 0x7fff + ((u >> 16) & 1)) >> 16;
    return (unsigned short)r;
}
// R16: wave-local LDS producer->consumer fence
static __device__ __forceinline__ void wave_sync() {
    asm volatile("s_waitcnt lgkmcnt(0)" ::: "memory");
    __builtin_amdgcn_sched_barrier(0);
}
static __device__ __forceinline__ void pkfma(f32x2& acc, f32x2 ab, f32x2 e2) {
    asm("v_pk_fma_f32 %0, %1, %2, %0" : "+v"(acc) : "v"(ab), "v"(e2));
}
static __device__ __forceinline__ void fma8pk(uint4 v, f32x2 e2, f32x2* acc) {
    f32x2 p;
    p.x = __uint_as_float(v.x << 16); p.y = __uint_as_float(v.x & 0xffff0000u);
    pkfma(acc[0], p, e2);
    p.x = __uint_as_float(v.y << 16); p.y = __uint_as_float(v.y & 0xffff0000u);
    pkfma(acc[1], p, e2);
    p.x = __uint_as_float(v.z << 16); p.y = __uint_as_float(v.z & 0xffff0000u);
    pkfma(acc[2], p, e2);
    p.x = __uint_as_float(v.w << 16); p.y = __uint_as_float(v.w & 0xffff0000u);
    pkfma(acc[3], p, e2);
}
// R14: bf16 dot2 hot loop (v_perm pair-build + v_dot2_f32_bf16)
static __device__ __forceinline__ void dot2bf(float& acc, unsigned px, unsigned pe) {
    asm("v_dot2_f32_bf16 %0, %1, %2, %0" : "+v"(acc) : "v"(px), "v"(pe));
}
static __device__ __forceinline__ void dot8x2(uint4 a, uint4 b, unsigned pe, float* acc) {
    unsigned p;
    p = __builtin_amdgcn_perm(a.x, b.x, 0x01000504u); dot2bf(acc[0], p, pe);
    p = __builtin_amdgcn_perm(a.x, b.x, 0x03020706u); dot2bf(acc[1], p, pe);
    p = __builtin_amdgcn_perm(a.y, b.y, 0x01000504u); dot2bf(acc[2], p, pe);
    p = __builtin_amdgcn_perm(a.y, b.y, 0x03020706u); dot2bf(acc[3], p, pe);
    p = __builtin_amdgcn_perm(a.z, b.z, 0x01000504u); dot2bf(acc[4], p, pe);
    p = __builtin_amdgcn_perm(a.z, b.z, 0x03020706u); dot2bf(acc[5], p, pe);
    p = __builtin_amdgcn_perm(a.w, b.w, 0x01000504u); dot2bf(acc[6], p, pe);
    p = __builtin_amdgcn_perm(a.w, b.w, 0x03020706u); dot2bf(acc[7], p, pe);
}

// ---- fused: x->bf16 + mean | deg count + edge slot | weight transpose-casts ----
__global__ __launch_bounds__(256) void k_pre(
    const float* __restrict__ x, unsigned short* __restrict__ xb, float* __restrict__ xmean,
    const int* __restrict__ ei, int* __restrict__ deg, int* __restrict__ epos,
    const float* __restrict__ w1, const float* __restrict__ w2,
    unsigned short* __restrict__ w1t, unsigned short* __restrict__ w2t) {
    int b = blockIdx.x, t = threadIdx.x;
    if (b < PREP_BLKS) {
        int wave = t >> 6, lane = t & 63;
        int n = b * 4 + wave;
        float2 v = *(const float2*)(x + (size_t)n * IN_CH + lane * 2);
        ushort2 o;
        o.x = f2bf(v.x); o.y = f2bf(v.y);
        *(ushort2*)(xb + (size_t)n * IN_CH + lane * 2) = o;
        float s = wave_sum(v.x + v.y);
        if (lane == 0) xmean[n] = s * (1.0f / 128.0f);
    } else if (b < PREP_BLKS + DEG_BLKS) {
        int e = (b - PREP_BLKS) * 256 + t;
        int d = ei[EREAL + e];
        epos[e] = atomicAdd(&deg[d], 1);
    } else {
        int idx = (b - PREP_BLKS - DEG_BLKS) * 256 + t;
        if (idx < HC * IN_CH) {
            int n = idx / IN_CH, k = idx % IN_CH;
            w1t[idx] = f2bf(w1[(size_t)k * HC + n]);
        } else {
            int j = idx - HC * IN_CH;
            int n = j / HC, k = j % HC;
            w2t[j] = f2bf(w2[(size_t)k * HC + n]);
        }
    }
}

// ---- scan degrees -> rowptr; write self-loop at slot 0 of each segment ----
__global__ __launch_bounds__(1024) void k_scan(const int* __restrict__ deg, int* __restrict__ rowptr,
                                               int* __restrict__ csr) {
    __shared__ int sd[1024];
    int t = threadIdx.x;
    int base = t * 32;
    int loc[32];
    int s = 0;
#pragma unroll
    for (int j = 0; j < 32; j++) { int d = deg[base + j] + 1; loc[j] = d; s += d; }
    sd[t] = s; __syncthreads();
    for (int o = 1; o < 1024; o <<= 1) {
        int v = (t >= o) ? sd[t - o] : 0;
        __syncthreads();
        sd[t] += v;
        __syncthreads();
    }
    int run = sd[t] - s;  // exclusive prefix
#pragma unroll
    for (int j = 0; j < 32; j++) {
        rowptr[base + j] = run;
        csr[run] = base + j;   // self-loop at slot 0
        run += loc[j];
    }
    if (t == 1023) rowptr[NTN] = run;
}

// ---- bf16 MFMA GEMM (+ optional fused CSR-fill blocks at by >= GEMM_YB) ----
__global__ __launch_bounds__(256) void k_gemm_mfma(
    const unsigned short* __restrict__ A, const unsigned short* __restrict__ Bt, int K,
    const float* __restrict__ attS, const float* __restrict__ attD,
    unsigned short* __restrict__ Cout, float* __restrict__ aS, float* __restrict__ aD,
    const int* __restrict__ ei, const int* __restrict__ epos,
    const int* __restrict__ rowptr, int* __restrict__ csr) {
    __shared__ unsigned short As[128][72];
    __shared__ unsigned short Bs[64][72];
    const int t = threadIdx.x;
    const int bx = blockIdx.x, by = blockIdx.y;
    if (by >= GEMM_YB) {
        int e = (((by - GEMM_YB) * 4 + bx)) * 256 + t;
        int s = ei[e], d = ei[EREAL + e];
        csr[rowptr[d] + 1 + epos[e]] = s;
        return;
    }
    const int lane = t & 63, wave = t >> 6;
    const int quad = lane >> 4, l16 = lane & 15;
    const int arow = t >> 1, acol = (t & 1) * 32;
    const int brow = t >> 2, bcol = (t & 3) * 16;
    const unsigned short* Ag = A + (size_t)(by * 128 + arow) * K + acol;
    const unsigned short* Bg = Bt + (size_t)(bx * 64 + brow) * K + bcol;
    f32x4 acc[2][4] = {};
    for (int k0 = 0; k0 < K; k0 += 64) {
        uint4 a0 = *(const uint4*)(Ag + k0);
        uint4 a1 = *(const uint4*)(Ag + k0 + 8);
        uint4 a2 = *(const uint4*)(Ag + k0 + 16);
        uint4 a3 = *(const uint4*)(Ag + k0 + 24);
        uint4 b0 = *(const uint4*)(Bg + k0);
        uint4 b1 = *(const uint4*)(Bg + k0 + 8);
        __syncthreads();
        *(uint4*)&As[arow][acol +  0] = a0;
        *(uint4*)&As[arow][acol +  8] = a1;
        *(uint4*)&As[arow][acol + 16] = a2;
        *(uint4*)&As[arow][acol + 24] = a3;
        *(uint4*)&Bs[brow][bcol +  0] = b0;
        *(uint4*)&Bs[brow][bcol +  8] = b1;
        __syncthreads();
#pragma unroll
        for (int kc = 0; kc < 64; kc += 32) {
            bf16x8 af[2], bfr[4];
#pragma unroll
            for (int mt = 0; mt < 2; mt++)
                af[mt] = *(const bf16x8*)&As[wave * 32 + mt * 16 + l16][kc + quad * 8];
#pragma unroll
            for (int nt = 0; nt < 4; nt++)
                bfr[nt] = *(const bf16x8*)&Bs[nt * 16 + l16][kc + quad * 8];
#pragma unroll
            for (int mt = 0; mt < 2; mt++)
#pragma unroll
                for (int nt = 0; nt < 4; nt++)
                    acc[mt][nt] = __builtin_amdgcn_mfma_f32_16x16x32_bf16(af[mt], bfr[nt], acc[mt][nt], 0, 0, 0);
        }
    }
    float as_l[4], ad_l[4];
#pragma unroll
    for (int nt = 0; nt < 4; nt++) {
        int gcol = bx * 64 + nt * 16 + l16;
        as_l[nt] = attS[gcol];
        ad_l[nt] = attD[gcol];
    }
#pragma unroll
    for (int mt = 0; mt < 2; mt++) {
#pragma unroll
        for (int reg = 0; reg < 4; reg++) {
            int grow = by * 128 + wave * 32 + mt * 16 + quad * 4 + reg;
            float ps = 0.f, pd = 0.f;
#pragma unroll
            for (int nt = 0; nt < 4; nt++) {
                float v = acc[mt][nt][reg];
                Cout[(size_t)grow * HC + bx * 64 + nt * 16 + l16] = f2bf(v);
                ps += v * as_l[nt];
                pd += v * ad_l[nt];
            }
            for (int o = 8; o; o >>= 1) { ps += __shfl_xor(ps, o); pd += __shfl_xor(pd, o); }
            if (l16 == 0) { aS[grow * 4 + bx] = ps; aD[grow * 4 + bx] = pd; }
        }
    }
}

// ---- attention aggregate (R16: 1 wave = 1 node; waves retire independently) ----
__global__ __launch_bounds__(256) void k_agg(
    const unsigned short* __restrict__ xw, const float* __restrict__ aS, const float* __restrict__ aD,
    const int* __restrict__ rowptr, const int* __restrict__ csr,
    const float* __restrict__ bias, const float* __restrict__ poolw, const float* __restrict__ poolb,
    unsigned short* __restrict__ hout, float* __restrict__ xpre) {
    __shared__ float ea_s[4][CAP][4];
    __shared__ int   ss[4][CAP];       // row byte offsets (s * HC * 2)
    int t = threadIdx.x;
    int w = t >> 6, lane = t & 63;
    int n = blockIdx.x * 4 + w;
    int beg = rowptr[n], end = rowptr[n + 1];
    int deg = end - beg;
    float4 ad4 = *(const float4*)(aD + n * 4);
    float l0 = 0.f, l1 = 0.f, l2 = 0.f, l3 = 0.f;
    if (deg <= CAP) {
        for (int i = lane; i < deg; i += 64) {
            int s = csr[beg + i];
            ss[w][i] = s << 9;
            float4 as4 = *(const float4*)(aS + s * 4);
            float a0 = as4.x + ad4.x; a0 = a0 > 0.f ? a0 : 0.2f * a0;
            float a1 = as4.y + ad4.y; a1 = a1 > 0.f ? a1 : 0.2f * a1;
            float a2 = as4.z + ad4.z; a2 = a2 > 0.f ? a2 : 0.2f * a2;
            float a3 = as4.w + ad4.w; a3 = a3 > 0.f ? a3 : 0.2f * a3;
            float4 e4;
            e4.x = __expf(a0); e4.y = __expf(a1); e4.z = __expf(a2); e4.w = __expf(a3);
            *(float4*)&ea_s[w][i][0] = e4;
        }
        wave_sync();
    } else {
        for (int i = lane; i < deg; i += 64) {
            int s = csr[beg + i];
            float4 as4 = *(const float4*)(aS + s * 4);
            float a0 = as4.x + ad4.x; a0 = a0 > 0.f ? a0 : 0.2f * a0; l0 += __expf(a0);
            float a1 = as4.y + ad4.y; a1 = a1 > 0.f ? a1 : 0.2f * a1; l1 += __expf(a1);
            float a2 = as4.z + ad4.z; a2 = a2 > 0.f ? a2 : 0.2f * a2; l2 += __expf(a2);
            float a3 = as4.w + ad4.w; a3 = a3 > 0.f ? a3 : 0.2f * a3; l3 += __expf(a3);
        }
        l0 = wave_sum(l0); l1 = wave_sum(l1); l2 = wave_sum(l2); l3 = wave_sum(l3);
    }
    int l31 = lane & 31, hi = lane >> 5;
    int head = l31 >> 3;
    float acc8[8] = {};
    f32x2 accF[4] = {};
    unsigned tb = (unsigned)(l31 * 16);
    const char* xwb_ = (const char*)xw;
    if (deg <= CAP) {
        int i = 0;
        for (; i + 16 <= deg; i += 16) {
            int iA = i + 8 * hi;
            int o0 = ss[w][iA], o1 = ss[w][iA + 1], o2 = ss[w][iA + 2], o3 = ss[w][iA + 3];
            int o4 = ss[w][iA + 4], o5 = ss[w][iA + 5], o6 = ss[w][iA + 6], o7 = ss[w][iA + 7];
            float e0 = ea_s[w][iA][head],     e1 = ea_s[w][iA + 1][head];
            float e2 = ea_s[w][iA + 2][head], e3 = ea_s[w][iA + 3][head];
            float e4 = ea_s[w][iA + 4][head], e5 = ea_s[w][iA + 5][head];
            float e6 = ea_s[w][iA + 6][head], e7 = ea_s[w][iA + 7][head];
            uint4 v0 = *(const uint4*)(xwb_ + ((unsigned)o0 + tb));
            uint4 v1 = *(const uint4*)(xwb_ + ((unsigned)o1 + tb));
            uint4 v2 = *(const uint4*)(xwb_ + ((unsigned)o2 + tb));
            uint4 v3 = *(const uint4*)(xwb_ + ((unsigned)o3 + tb));
            uint4 v4 = *(const uint4*)(xwb_ + ((unsigned)o4 + tb));
            uint4 v5 = *(const uint4*)(xwb_ + ((unsigned)o5 + tb));
            uint4 v6 = *(const uint4*)(xwb_ + ((unsigned)o6 + tb));
            uint4 v7 = *(const uint4*)(xwb_ + ((unsigned)o7 + tb));
            unsigned p01, p23, p45, p67;
            asm("v_cvt_pk_bf16_f32 %0, %1, %2" : "=v"(p01) : "v"(e0), "v"(e1));
            asm("v_cvt_pk_bf16_f32 %0, %1, %2" : "=v"(p23) : "v"(e2), "v"(e3));
            asm("v_cvt_pk_bf16_f32 %0, %1, %2" : "=v"(p45) : "v"(e4), "v"(e5));
            asm("v_cvt_pk_bf16_f32 %0, %1, %2" : "=v"(p67) : "v"(e6), "v"(e7));
            dot8x2(v0, v1, p01, acc8);
            dot8x2(v2, v3, p23, acc8);
            dot8x2(v4, v5, p45, acc8);
            dot8x2(v6, v7, p67, acc8);
        }
        for (; i + 8 <= deg; i += 8) {
            int iA = i + 4 * hi;
            int o0 = ss[w][iA], o1 = ss[w][iA + 1], o2 = ss[w][iA + 2], o3 = ss[w][iA + 3];
            float e0 = ea_s[w][iA][head],     e1 = ea_s[w][iA + 1][head];
            float e2 = ea_s[w][iA + 2][head], e3 = ea_s[w][iA + 3][head];
            uint4 v0 = *(const uint4*)(xwb_ + ((unsigned)o0 + tb));
            uint4 v1 = *(const uint4*)(xwb_ + ((unsigned)o1 + tb));
            uint4 v2 = *(const uint4*)(xwb_ + ((unsigned)o2 + tb));
            uint4 v3 = *(const uint4*)(xwb_ + ((unsigned)o3 + tb));
            unsigned p01, p23;
            asm("v_cvt_pk_bf16_f32 %0, %1, %2" : "=v"(p01) : "v"(e0), "v"(e1));
            asm("v_cvt_pk_bf16_f32 %0, %1, %2" : "=v"(p23) : "v"(e2), "v"(e3));
            dot8x2(v0, v1, p01, acc8);
            dot8x2(v2, v3, p23, acc8);
        }
        for (; i + 4 <= deg; i += 4) {
            int iA = i + 2 * hi;
            int o0 = ss[w][iA], o1 = ss[w][iA + 1];
            float e0 = ea_s[w][iA][head], e1 = ea_s[w][iA + 1][head];
            unsigned pe;
            asm("v_cvt_pk_bf16_f32 %0, %1, %2" : "=v"(pe) : "v"(e0), "v"(e1));
            uint4 v0 = *(const uint4*)(xwb_ + ((unsigned)o0 + tb));
            uint4 v1 = *(const uint4*)(xwb_ + ((unsigned)o1 + tb));
            dot8x2(v0, v1, pe, acc8);
        }
        if (i < deg) {
            int iA = i + 2 * hi, iB = iA + 1;
            bool okA = iA < deg, okB = iB < deg;
            int ia = okA ? iA : 0;
            int ib = okB ? iB : 0;
            int o0 = ss[w][ia], o1 = ss[w][ib];
            float e0 = okA ? ea_s[w][ia][head] : 0.f;
            float e1 = okB ? ea_s[w][ib][head] : 0.f;
            unsigned pe;
            asm("v_cvt_pk_bf16_f32 %0, %1, %2" : "=v"(pe) : "v"(e0), "v"(e1));
            uint4 v0 = *(const uint4*)(xwb_ + ((unsigned)o0 + tb));
            uint4 v1 = *(const uint4*)(xwb_ + ((unsigned)o1 + tb));
            dot8x2(v0, v1, pe, acc8);
        }
    } else {
        const unsigned short* xwc = xw + l31 * 8;
        float adh = head == 0 ? ad4.x : head == 1 ? ad4.y : head == 2 ? ad4.z : ad4.w;
        for (int i = beg; i < end; i += 2) {
            int idx = i + hi;
            bool ok = idx < end;
            int sA = csr[ok ? idx : beg];
            float a = aS[sA * 4 + head] + adh;
            a = a > 0.f ? a : 0.2f * a;
            float eA = ok ? __expf(a) : 0.f;
            uint4 vA = *(const uint4*)(xwc + (size_t)sA * HC);
            f32x2 eA2; eA2.x = eA; eA2.y = eA;
            fma8pk(vA, eA2, accF);
        }
    }
    float r8[8];
#pragma unroll
    for (int j = 0; j < 8; j++) {
        float v = acc8[j] + accF[j >> 1][j & 1];
        v += __shfl_xor(v, 32);
        r8[j] = v;
    }
    if (hi == 0) {
        float ilh;
        if (deg <= CAP) {
            float lsum = 0.f;
            for (int j = (l31 & 7); j < deg; j += 8) lsum += ea_s[w][j][head];
            lsum += __shfl_xor(lsum, 1);
            lsum += __shfl_xor(lsum, 2);
            lsum += __shfl_xor(lsum, 4);
            ilh = 1.0f / (lsum + 1e-16f);
        } else {
            float lh = head == 0 ? l0 : head == 1 ? l1 : head == 2 ? l2 : l3;
            ilh = 1.0f / (lh + 1e-16f);
        }
        float4 b0 = *(const float4*)(bias + l31 * 8);
        float4 b1 = *(const float4*)(bias + l31 * 8 + 4);
        float r[8];
        r[0] = r8[0] * ilh + b0.x;
        r[1] = r8[1] * ilh + b0.y;
        r[2] = r8[2] * ilh + b0.z;
        r[3] = r8[3] * ilh + b0.w;
        r[4] = r8[4] * ilh + b1.x;
        r[5] = r8[5] * ilh + b1.y;
        r[6] = r8[6] * ilh + b1.z;
        r[7] = r8[7] * ilh + b1.w;
#pragma unroll
        for (int j = 0; j < 8; j++) r[j] = r[j] > 0.f ? r[j] : expm1f(r[j]);
        if (hout) {
            uint4 o;
            o.x = (unsigned)f2bf(r[0]) | ((unsigned)f2bf(r[1]) << 16);
            o.y = (unsigned)f2bf(r[2]) | ((unsigned)f2bf(r[3]) << 16);
            o.z = (unsigned)f2bf(r[4]) | ((unsigned)f2bf(r[5]) << 16);
            o.w = (unsigned)f2bf(r[6]) | ((unsigned)f2bf(r[7]) << 16);
            *(uint4*)(hout + (size_t)n * HC + l31 * 8) = o;
        }
        float4 w0 = *(const float4*)(poolw + l31 * 8);
        float4 w1v = *(const float4*)(poolw + l31 * 8 + 4);
        float p = r[0] * w0.x + r[1] * w0.y + r[2] * w0.z + r[3] * w0.w +
                  r[4] * w1v.x + r[5] * w1v.y + r[6] * w1v.z + r[7] * w1v.w;
        for (int o = 16; o; o >>= 1) p += __shfl_xor(p, o);
        if (l31 == 0) xpre[n] = p + poolb[0];
    }
}

// ---- LayerNorm x3 (proven R16 kernel): blocks 0-15 xmean, 16-31 x1pre, 32-47 x2pre ----
__global__ __launch_bounds__(256) void k_ln3(const float* __restrict__ xmean, const float* __restrict__ x1pre,
                                             const float* __restrict__ x2pre, const float* __restrict__ lw,
                                             const float* __restrict__ lb, float* __restrict__ feat) {
    __shared__ float r0[256], r1[256];
    int b = blockIdx.x, t = threadIdx.x;
    int row = b & 15, seg = b >> 4;
    const float* src = (seg == 0 ? xmean : seg == 1 ? x1pre : x2pre) + (size_t)row * NN;
    float* dst = feat + (size_t)row * (3 * NN) + seg * NN;
    float v[8];
    float s = 0.f, s2 = 0.f;
#pragma unroll
    for (int j = 0; j < 8; j++) {
        float x = src[t + j * 256];
        v[j] = x; s += x; s2 += x * x;
    }
    r0[t] = s; r1[t] = s2; __syncthreads();
    for (int o = 128; o; o >>= 1) {
        if (t < o) { r0[t] += r0[t + o]; r1[t] += r1[t + o]; }
        __syncthreads();
    }
    float mu = r0[0] * (1.0f / NN);
    float var = r1[0] * (1.0f / NN) - mu * mu;
    float rs = rsqrtf(var + 1e-5f);
#pragma unroll
    for (int j = 0; j < 8; j++) {
        int idx = t + j * 256;
        dst[idx] = (v[j] - mu) * rs * lw[idx] + lb[idx];
    }
}

// ---- split-K FC (proven R16 kernel): In staged to LDS, compile-time KC ----
template<int KC>
__global__ __launch_bounds__(256) void k_fc_splitk(const float* __restrict__ In, const float* __restrict__ W,
                                                   float* __restrict__ partial, int K, int Nc) {
    __shared__ float in_s[16][KC];
    int t = threadIdx.x;
    int k0 = blockIdx.y * KC;
    for (int idx = t; idx < 16 * KC; idx += 256) {
        int r = idx / KC, kk = idx % KC;
        in_s[r][kk] = In[(size_t)r * K + k0 + kk];
    }
    __syncthreads();
    int col = blockIdx.x * 256 + t;
    if (col < Nc) {
        float acc[16] = {};
#pragma unroll
        for (int kk = 0; kk < KC; kk++) {
            float w = W[(size_t)(k0 + kk) * Nc + col];
#pragma unroll
            for (int r = 0; r < 16; r++) acc[r] += in_s[r][kk] * w;
        }
        float* pp = partial + ((size_t)blockIdx.y * 16) * Nc + col;
#pragma unroll
        for (int r = 0; r < 16; r++) pp[(size_t)r * Nc] = acc[r];
    }
}

// ---- enc1 split-K; recomputes its e0 slice from part0 (proven R20). grid (2,64); KC=16 ----
__global__ __launch_bounds__(256) void k_fc1(
    const float* __restrict__ part0, const float* __restrict__ b0,
    const float* __restrict__ W, float* __restrict__ partial) {
    __shared__ float in_s[16][16];
    int t = threadIdx.x;
    int bx = blockIdx.x, by = blockIdx.y;
    int k0 = by * 16;
    {
        int r = t >> 4, kk = t & 15;
        float s = 0.f;
#pragma unroll 8
        for (int k = 0; k < 96; k++) s += part0[((size_t)(k * 16) + r) * FC0 + (k0 + kk)];
        s += b0[k0 + kk];
        in_s[r][kk] = s > 0.f ? s : expm1f(s);
    }
    __syncthreads();
    int col = bx * 256 + t;
    float acc[16] = {};
#pragma unroll
    for (int kk = 0; kk < 16; kk++) {
        float wv = W[(size_t)(k0 + kk) * FC1 + col];
#pragma unroll
        for (int r = 0; r < 16; r++) acc[r] += in_s[r][kk] * wv;
    }
    float* pp = partial + ((size_t)by * 16) * FC1 + col;
#pragma unroll
    for (int r = 0; r < 16; r++) pp[(size_t)r * FC1] = acc[r];
}

// ---- enc2 split-K; recomputes its e1 slice from part1 (proven R20). grid (32); KC=16 ----
__global__ __launch_bounds__(256) void k_fc2(
    const float* __restrict__ part1, const float* __restrict__ b1,
    const float* __restrict__ W, float* __restrict__ partial) {
    __shared__ float in_s[16][16];
    int t = threadIdx.x;
    int by = blockIdx.x;
    int k0 = by * 16;
    {
        int r = t >> 4, kk = t & 15;
        float s = 0.f;
#pragma unroll 8
        for (int k = 0; k < 64; k++) s += part1[((size_t)(k * 16) + r) * FC1 + (k0 + kk)];
        s += b1[k0 + kk];
        in_s[r][kk] = s > 0.f ? s : expm1f(s);
    }
    __syncthreads();
    if (t < OMIC) {
        int col = t;
        float acc[16] = {};
#pragma unroll
        for (int kk = 0; kk < 16; kk++) {
            float wv = W[(size_t)(k0 + kk) * OMIC + col];
#pragma unroll
            for (int r = 0; r < 16; r++) acc[r] += in_s[r][kk] * wv;
        }
        float* pp = partial + ((size_t)by * 16) * OMIC + col;
#pragma unroll
        for (int r = 0; r < 16; r++) pp[(size_t)r * OMIC] = acc[r];
    }
}

// ---- last layer; recomputes e2 from part2 in-block (proven R20). 1 block ----
__global__ __launch_bounds__(256) void k_last2(
    const float* __restrict__ part2, const float* __restrict__ b2,
    const float* __restrict__ W, const float* __restrict__ bl, float* __restrict__ Out) {
    __shared__ float e2s[16][OMIC];
    int t = threadIdx.x;
    for (int idx = t; idx < 16 * OMIC; idx += 256) {
        int r = idx >> 7, c = idx & 127;
        float s = 0.f;
#pragma unroll 8
        for (int k = 0; k < 32; k++) s += part2[((size_t)(k * 16) + r) * OMIC + c];
        s += b2[c];
        e2s[r][c] = s > 0.f ? s : expm1f(s);
    }
    __syncthreads();
    int r = t >> 4, c = (t >> 3) & 1, ksub = t & 7;
    float s = 0.f;
#pragma unroll
    for (int k = 0; k < OMIC / 8; k++) s += e2s[r][k * 8 + ksub] * W[(k * 8 + ksub) * OUTD + c];
    for (int o = 1; o < 8; o <<= 1) s += __shfl_xor(s, o);
    if (ksub == 0) Out[r * OUTD + c] = s + bl[c];
}

extern "C" void kernel_launch(void* const* d_in, const int* in_sizes, int n_in,
                              void* d_out, int out_size, void* d_ws, size_t ws_size,
                              hipStream_t stream) {
    (void)in_sizes; (void)n_in; (void)out_size; (void)ws_size;
    const float* x        = (const float*)d_in[0];
    const int*   ei       = (const int*)d_in[1];
    const float* w1       = (const float*)d_in[2];
    const float* att_src1 = (const float*)d_in[3];
    const float* att_dst1 = (const float*)d_in[4];
    const float* bias1    = (const float*)d_in[5];
    const float* pool1_w  = (const float*)d_in[6];
    const float* pool1_b  = (const float*)d_in[7];
    const float* w2       = (const float*)d_in[8];
    const float* att_src2 = (const float*)d_in[9];
    const float* att_dst2 = (const float*)d_in[10];
    const float* bias2    = (const float*)d_in[11];
    const float* pool2_w  = (const float*)d_in[12];
    const float* pool2_b  = (const float*)d_in[13];
    const float* ln_w     = (const float*)d_in[14];
    const float* ln_b     = (const float*)d_in[15];
    const float* enc0_w   = (const float*)d_in[16];
    const float* enc0_b   = (const float*)d_in[17];
    const float* enc1_w   = (const float*)d_in[18];
    const float* enc1_b   = (const float*)d_in[19];
    const float* enc2_w   = (const float*)d_in[20];
    const float* enc2_b   = (const float*)d_in[21];
    const float* last_w   = (const float*)d_in[22];
    const float* last_b   = (const float*)d_in[23];
    float* out = (float*)d_out;

    char* p = (char*)d_ws;
    auto alloc = [&](size_t bytes) -> void* {
        void* r = (void*)p;
        p += (bytes + 255) & ~(size_t)255;
        return r;
    };
    unsigned short* xwb  = (unsigned short*)alloc((size_t)NTN * HC * 2);
    unsigned short* hb   = (unsigned short*)alloc((size_t)NTN * HC * 2);
    unsigned short* xb   = (unsigned short*)alloc((size_t)NTN * IN_CH * 2);
    unsigned short* w1t  = (unsigned short*)alloc((size_t)HC * IN_CH * 2);
    unsigned short* w2t  = (unsigned short*)alloc((size_t)HC * HC * 2);
    float* a_src  = (float*)alloc((size_t)NTN * 4 * 4);
    float* a_dst  = (float*)alloc((size_t)NTN * 4 * 4);
    float* xmean  = (float*)alloc((size_t)NTN * 4);
    float* x1pre  = (float*)alloc((size_t)NTN * 4);
    float* x2pre  = (float*)alloc((size_t)NTN * 4);
    float* feat   = (float*)alloc((size_t)BB * 3 * NN * 4);
    float* part0  = (float*)alloc((size_t)96 * 16 * FC0 * 4);
    float* part1  = (float*)alloc((size_t)64 * 16 * FC1 * 4);
    float* part2  = (float*)alloc((size_t)32 * 16 * OMIC * 4);
    int*   deg    = (int*)alloc((size_t)NTN * 4);
    int*   rowptr = (int*)alloc((size_t)(NTN + 1) * 4);
    int*   epos   = (int*)alloc((size_t)EREAL * 4);
    int*   csr    = (int*)alloc((size_t)ETOT * 4);

    hipMemsetAsync(deg, 0, (size_t)NTN * 4, stream);

    k_pre<<<PREP_BLKS + DEG_BLKS + CASTW_BLKS, 256, 0, stream>>>(
        x, xb, xmean, ei, deg, epos, w1, w2, w1t, w2t);
    k_scan<<<1, 1024, 0, stream>>>(deg, rowptr, csr);

    // GAT layer 1 (+ fused CSR fill blocks)
    k_gemm_mfma<<<dim3(4, GEMM_YB + FILL_YB), 256, 0, stream>>>(
        xb, w1t, IN_CH, att_src1, att_dst1, xwb, a_src, a_dst, ei, epos, rowptr, csr);
    k_agg<<<NTN / 4, 256, 0, stream>>>(xwb, a_src, a_dst, rowptr, csr, bias1, pool1_w, pool1_b, hb, x1pre);

    // GAT layer 2
    k_gemm_mfma<<<dim3(4, GEMM_YB), 256, 0, stream>>>(
        hb, w2t, HC, att_src2, att_dst2, xwb, a_src, a_dst, ei, epos, rowptr, csr);
    k_agg<<<NTN / 4, 256, 0, stream>>>(xwb, a_src, a_dst, rowptr, csr, bias2, pool2_w, pool2_b, (unsigned short*)nullptr, x2pre);

    // R21 head: proven ln3 + splitk0, then fused consumers (fc1/fc2/last2)
    k_ln3<<<48, 256, 0, stream>>>(xmean, x1pre, x2pre, ln_w, ln_b, feat);
    k_fc_splitk<64><<<dim3(4, 96), 256, 0, stream>>>(feat, enc0_w, part0, 3 * NN, FC0);
    k_fc1<<<dim3(2, 64), 256, 0, stream>>>(part0, enc0_b, enc1_w, part1);
    k_fc2<<<32, 256, 0, stream>>>(part1, enc1_b, enc2_w, part2);
    k_last2<<<1, 256, 0, stream>>>(part2, enc2_b, last_w, last_b, out);
}